// Round 9
// baseline (270.536 us; speedup 1.0000x reference)
//
#include <hip/hip_runtime.h>

typedef __attribute__((ext_vector_type(8))) short short8v;   // bf16x8 fragment
typedef __attribute__((ext_vector_type(4))) float float4v;   // fp32x4 accum
typedef unsigned short ushort;
typedef unsigned int uint;

namespace {

constexpr int Hh = 192, Ww = 192, Cc = 16, Oo = 64, Bb = 4;
constexpr int TH = 4, TW = 32, NPIX = 128, NT = 256;  // 4x32 tile, 2 threads/pixel

// Each feature = (vertical segment sum) + (horizontal segment sum), scaled by 1/n.
struct FD { int hasV; int vdj, vi0, vi1; int hasH; int hdi, hj0, hj1; float inv_n; };

constexpr FD FT[49] = {
    // 9 inner taps (i,j) row-major, n=1
    {1,-1,-1,-1, 0,0,0,0, 1.f}, {1, 0,-1,-1, 0,0,0,0, 1.f}, {1, 1,-1,-1, 0,0,0,0, 1.f},
    {1,-1, 0, 0, 0,0,0,0, 1.f}, {1, 0, 0, 0, 0,0,0,0, 1.f}, {1, 1, 0, 0, 0,0,0,0, 1.f},
    {1,-1, 1, 1, 0,0,0,0, 1.f}, {1, 0, 1, 1, 0,0,0,0, 1.f}, {1, 1, 1, 1, 0,0,0,0, 1.f},
    // ring5 (16)
    {1,-2,-2, 2, 1,-2,-1, 2, 1.f/9.f},
    {1,-1,-2, 2, 0,0,0,0, 0.2f},
    {1, 0,-2, 2, 0,0,0,0, 0.2f},
    {1, 1,-2, 2, 0,0,0,0, 0.2f},
    {1, 2,-2, 2, 1,-2,-2, 1, 1.f/9.f},
    {0,0,0,0, 1,-1,-2, 2, 0.2f},
    {0,0,0,0, 1,-1,-2, 2, 0.2f},
    {0,0,0,0, 1, 0,-2, 2, 0.2f},
    {0,0,0,0, 1, 0,-2, 2, 0.2f},
    {0,0,0,0, 1, 1,-2, 2, 0.2f},
    {0,0,0,0, 1, 1,-2, 2, 0.2f},
    {1,-2,-2, 2, 1, 2,-1, 2, 1.f/9.f},
    {1,-1,-2, 2, 0,0,0,0, 0.2f},
    {1, 0,-2, 2, 0,0,0,0, 0.2f},
    {1, 1,-2, 2, 0,0,0,0, 0.2f},
    {1, 2,-2, 2, 1, 2,-2, 1, 1.f/9.f},
    // ring7 (24)
    {1,-3,-3,11, 1,-3,-2,21, 1.f/39.f},
    {1,-2,-3,11, 0,0,0,0, 1.f/15.f},
    {1,-1,-3,11, 0,0,0,0, 1.f/15.f},
    {1, 0,-3,11, 0,0,0,0, 1.f/15.f},
    {1, 1,-3,11, 0,0,0,0, 1.f/15.f},
    {1, 2,-3,11, 0,0,0,0, 1.f/15.f},
    {1, 3,-3,11, 1,-3,-21, 2, 1.f/39.f},
    {0,0,0,0, 1,-2,-3,21, 0.04f},
    {0,0,0,0, 1,-2,-21,3, 0.04f},
    {0,0,0,0, 1,-1,-3,21, 0.04f},
    {0,0,0,0, 1,-1,-21,3, 0.04f},
    {0,0,0,0, 1, 0,-3,21, 0.04f},
    {0,0,0,0, 1, 0,-21,3, 0.04f},
    {0,0,0,0, 1, 1,-3,21, 0.04f},
    {0,0,0,0, 1, 1,-21,3, 0.04f},
    {0,0,0,0, 1, 2,-3,21, 0.04f},
    {0,0,0,0, 1, 2,-21,3, 0.04f},
    {1,-3,-11,3, 1, 3,-2,21, 1.f/39.f},
    {1,-2,-11,3, 0,0,0,0, 1.f/15.f},
    {1,-1,-11,3, 0,0,0,0, 1.f/15.f},
    {1, 0,-11,3, 0,0,0,0, 1.f/15.f},
    {1, 1,-11,3, 0,0,0,0, 1.f/15.f},
    {1, 2,-11,3, 0,0,0,0, 1.f/15.f},
    {1, 3,-11,3, 1, 3,-21,2, 1.f/39.f},
};

// reflect-pad(3) + clip index map; valid for u in [-21, 212]
__device__ __forceinline__ int mapIdx(int u) {
    if (u < 0) { u = -u; if (u > 3) u = 3; }
    else if (u > 191) { u = 382 - u; if (u < 188) u = 188; }
    return u;
}

__device__ __forceinline__ ushort f2bf(float f) {   // RNE fp32->bf16 bits
    uint u = __builtin_bit_cast(uint, f);
    u += 0x7FFFu + ((u >> 16) & 1u);
    return (ushort)(u >> 16);
}

// LDS layout (bytes): union { E[26][76]f (7904) | PVt[27][40]f (+4320) | PHt[10][76]f (+3040) = 15264 }
//                     aliased with featB[128][66]u16 (16896)  -> region size 16896
// wlds[64][72]u16 (9216) separate.  Total 26112 B -> 6 blocks/CU.
constexpr int OFF_PVT = 26 * 76 * 4;              // 7904
constexpr int OFF_PHT = OFF_PVT + 27 * 40 * 4;    // 12224
constexpr int SM_BYTES = 128 * 66 * 2;            // 16896

__global__ __launch_bounds__(NT, 4)
void fova_v9(const float* __restrict__ x, const float* __restrict__ wgt,
             const float* __restrict__ bias, float* __restrict__ out)
{
    __shared__ __align__(16) char smraw[SM_BYTES];
    __shared__ ushort wlds[64][72];    // bf16 weight slice [o][k], 144B rows (16B-aligned)

    float (*E)[76]      = reinterpret_cast<float(*)[76]>(smraw);
    float (*PVt)[40]    = reinterpret_cast<float(*)[40]>(smraw + OFF_PVT);
    float (*PHt)[76]    = reinterpret_cast<float(*)[76]>(smraw + OFF_PHT);
    ushort (*featB)[66] = reinterpret_cast<ushort(*)[66]>(smraw);

    const int tid  = threadIdx.x;
    const int lane = tid & 63;
    const int wv   = tid >> 6;          // wave id 0..3
    const int half = tid >> 7;          // 0: feats 0..24, 1: feats 25..48 (wave-uniform)
    const int pix  = tid & 127;         // pixel id within tile
    const int w0   = blockIdx.x * TW;
    const int h0   = blockIdx.y * TH;
    const int b    = blockIdx.z;
    const int ph   = pix >> 5;          // pixel row 0..3
    const int pw   = pix & 31;
    const int ur   = ph + 11;           // pixel row in extended coords
    const int vcc  = pw + 21;           // pixel col in extended coords

    float4v acc[4][2];                  // [ob][nbl]: wave wv owns pixels wv*32 .. wv*32+31
#pragma unroll
    for (int i = 0; i < 4; ++i)
#pragma unroll
        for (int j = 0; j < 2; ++j) acc[i][j] = (float4v)(0.f);

    // one-time: zero weight pad slots k=49..63 (never rewritten)
    if (tid < 64) {
#pragma unroll
        for (int f = 49; f < 64; ++f) wlds[tid][f] = 0;
    }

    for (int c = 0; c < Cc; ++c) {
        // ---- phase 1: stage E(c) + stage W(c) into LDS ----
        {
            const float* xp = x + (size_t)(b * Cc + c) * Hh * Ww;
            for (int idx = tid; idx < 26 * 74; idx += NT) {
                int uu = idx / 74, vvv = idx - uu * 74;
                E[uu][vvv] = xp[mapIdx(h0 + uu - 11) * Ww + mapIdx(w0 + vvv - 21)];
            }
            const float* wc = wgt + c * 49;
            for (int idx = tid; idx < 64 * 49; idx += NT) {
                int o = idx / 49, f = idx - o * 49;
                wlds[o][f] = f2bf(wc[o * 784 + f]);
            }
        }
        __syncthreads();

        // ---- phase 2: serial prefix scans ----
        if (tid < 38) {
            int cv = tid;                 // abs col 18+tid
            float r = 0.f;
            PVt[0][cv] = 0.f;
#pragma unroll
            for (int rr = 0; rr < 26; ++rr) { r += E[rr][18 + cv]; PVt[rr + 1][cv] = r; }
        }
        if (tid >= 96 && tid < 106) {
            int rv = tid - 96;            // abs row 8+rv
            float r = 0.f;
            PHt[rv][0] = 0.f;
#pragma unroll
            for (int s = 0; s < 74; ++s) { r += E[8 + rv][s]; PHt[rv][s + 1] = r; }
        }
        __syncthreads();

        // ---- phase 3a: this half's features into registers ----
        float feat[25];
        if (half == 0) {
#pragma unroll
            for (int f = 0; f < 25; ++f) {
                float s = 0.f;
                if (FT[f].hasV) {
                    int cv = pw + 3 + FT[f].vdj;
                    s += PVt[ur + FT[f].vi1 + 1][cv] - PVt[ur + FT[f].vi0][cv];
                }
                if (FT[f].hasH) {
                    int rv = ph + 3 + FT[f].hdi;
                    s += PHt[rv][vcc + FT[f].hj1 + 1] - PHt[rv][vcc + FT[f].hj0];
                }
                feat[f] = s * FT[f].inv_n;
            }
        } else {
#pragma unroll
            for (int f = 25; f < 49; ++f) {
                float s = 0.f;
                if (FT[f].hasV) {
                    int cv = pw + 3 + FT[f].vdj;
                    s += PVt[ur + FT[f].vi1 + 1][cv] - PVt[ur + FT[f].vi0][cv];
                }
                if (FT[f].hasH) {
                    int rv = ph + 3 + FT[f].hdi;
                    s += PHt[rv][vcc + FT[f].hj1 + 1] - PHt[rv][vcc + FT[f].hj0];
                }
                feat[f - 25] = s * FT[f].inv_n;
            }
        }
        __syncthreads();   // all E/PVt/PHt reads complete before featB overwrites them

        // ---- phase 3b: write featB (aliases E/PVt/PHt region) ----
        if (half == 0) {
#pragma unroll
            for (int f = 0; f < 25; ++f) featB[pix][f] = f2bf(feat[f]);
        } else {
#pragma unroll
            for (int f = 25; f < 49; ++f) featB[pix][f] = f2bf(feat[f - 25]);
#pragma unroll
            for (int f = 49; f < 64; ++f) featB[pix][f] = 0;
        }
        __syncthreads();

        // ---- phase 4: contraction via MFMA (A from wlds b128, B from featB) ----
        {
            const int olo = lane & 15, kg = lane >> 4;
#pragma unroll
            for (int kc = 0; kc < 2; ++kc) {
                const int k0 = kc * 32 + kg * 8;          // 16B aligned in wlds
                short8v afr[4];
#pragma unroll
                for (int ob = 0; ob < 4; ++ob) {
                    const int o = ob * 16 + olo;
                    afr[ob] = *(const short8v*)(&wlds[o][k0]);
                }
                short8v bfr[2];
#pragma unroll
                for (int nbl = 0; nbl < 2; ++nbl) {
                    const int p = wv * 32 + nbl * 16 + olo;
                    const uint* bp = (const uint*)(&featB[p][k0]);
                    uint4 u;
                    u.x = bp[0]; u.y = bp[1]; u.z = bp[2]; u.w = bp[3];
                    bfr[nbl] = __builtin_bit_cast(short8v, u);
                }
#pragma unroll
                for (int ob = 0; ob < 4; ++ob)
#pragma unroll
                    for (int nbl = 0; nbl < 2; ++nbl)
                        acc[ob][nbl] = __builtin_amdgcn_mfma_f32_16x16x32_bf16(
                            afr[ob], bfr[nbl], acc[ob][nbl], 0, 0, 0);
            }
        }
        __syncthreads();   // featB (aliased with E) fully read before next stage
    }

    // ---- epilogue: D frag: col(pixel)=lane&15, row(o)=(lane>>4)*4+reg ----
#pragma unroll
    for (int ob = 0; ob < 4; ++ob)
#pragma unroll
        for (int nbl = 0; nbl < 2; ++nbl) {
            const int p = wv * 32 + nbl * 16 + (lane & 15);
            const int h = h0 + (p >> 5), w = w0 + (p & 31);
            const int o0 = ob * 16 + ((lane >> 4) << 2);
            float4v a = acc[ob][nbl];
#pragma unroll
            for (int r = 0; r < 4; ++r) {
                const int o = o0 + r;
                out[(((size_t)b * Oo + o) * Hh + h) * Ww + w] = a[r] + bias[o];
            }
        }
}

} // namespace

extern "C" void kernel_launch(void* const* d_in, const int* in_sizes, int n_in,
                              void* d_out, int out_size, void* d_ws, size_t ws_size,
                              hipStream_t stream) {
    (void)in_sizes; (void)n_in; (void)d_ws; (void)ws_size; (void)out_size;
    const float* x    = (const float*)d_in[0];
    const float* wgt  = (const float*)d_in[1];
    const float* bias = (const float*)d_in[2];
    float* out        = (float*)d_out;

    dim3 grid(Ww / TW, Hh / TH, Bb);   // 6 x 48 x 4 = 1152 blocks, 4 waves each
    dim3 block(NT);
    fova_v9<<<grid, block, 0, stream>>>(x, wgt, bias, out);
}